// Round 11
// baseline (6672.979 us; speedup 1.0000x reference)
//
#include <hip/hip_runtime.h>

#define NS 512
#define NA 256
#define PGD_ITERS 300
#define POWER_ITERS 30

typedef _Float16 f16;
typedef __attribute__((ext_vector_type(4))) _Float16 f16x4;
typedef __attribute__((ext_vector_type(8))) _Float16 f16x8;
typedef __attribute__((ext_vector_type(4))) float f32x4;

// Per-sample LDS layout (bytes). Two samples per block -> 2x this, 86,528 B.
#define CSTR 260            // f32 staging row stride (elems)
#define TSTR 24             // f16 C^T tile row stride (elems) = 48 B
#define OFF_CH  16640       // STG: 16*260*4
#define OFF_CL  28928       // CH:  256*24*2
#define OFF_YY0 41216       // CL:  256*24*2
#define OFF_YY1 42240       // YY0: 256 f32
#define SAMPLE_BYTES 43264  // YY1: 256 f32
#define LDS_BYTES (2 * SAMPLE_BYTES)

// ---- cross-lane primitives (VALU DPP; zero DS-pipe traffic) ----
// SAFETY: all call sites have FULL exec; control flow around them is
// wave-uniform (scalar branches on readlane/readfirstlane results).
template<int CTRL>
__device__ __forceinline__ float dpp_add(float x) {
  const int r = __builtin_amdgcn_update_dpp(0, __float_as_int(x), CTRL, 0xF, 0xF, true);
  return x + __int_as_float(r);
}
template<int CTRL>
__device__ __forceinline__ float dpp_max(float x) {
  const int r = __builtin_amdgcn_update_dpp(0, __float_as_int(x), CTRL, 0xF, 0xF, true);
  return fmaxf(x, __int_as_float(r));
}
// 16-lane-row sum via rotation doubling: every lane gets its row's total
__device__ __forceinline__ float red16(float x) {
  x = dpp_add<0x121>(x);  // row_ror:1
  x = dpp_add<0x122>(x);  // row_ror:2
  x = dpp_add<0x124>(x);  // row_ror:4
  x = dpp_add<0x128>(x);  // row_ror:8
  return x;
}
// full-wave64 sum -> uniform scalar (row sums, then bcast15/31 ladder, lane63)
__device__ __forceinline__ float redwave_add(float x) {
  x = red16(x);
  { // += lane15 -> row1, lane47 -> row3  (rows 1,3 enabled)
    const int r = __builtin_amdgcn_update_dpp(0, __float_as_int(x), 0x142, 0xA, 0xF, true);
    x += __int_as_float(r);
  }
  { // += lane31 -> rows 2,3
    const int r = __builtin_amdgcn_update_dpp(0, __float_as_int(x), 0x143, 0xC, 0xF, true);
    x += __int_as_float(r);
  }
  return __int_as_float(__builtin_amdgcn_readlane(__float_as_int(x), 63));
}
__device__ __forceinline__ float redwave_max(float x) {
  x = dpp_max<0x121>(x);
  x = dpp_max<0x122>(x);
  x = dpp_max<0x124>(x);
  x = dpp_max<0x128>(x);
  { // masked-off rows get old=x -> fmax(x,x)=x (safe for negatives)
    const int r = __builtin_amdgcn_update_dpp(__float_as_int(x), __float_as_int(x), 0x142, 0xA, 0xF, false);
    x = fmaxf(x, __int_as_float(r));
  }
  {
    const int r = __builtin_amdgcn_update_dpp(__float_as_int(x), __float_as_int(x), 0x143, 0xC, 0xF, false);
    x = fmaxf(x, __int_as_float(r));
  }
  return __int_as_float(__builtin_amdgcn_readlane(__float_as_int(x), 63));
}
// uniform broadcast of an already-lane-uniform value
__device__ __forceinline__ float rfl(float x) {
  return __int_as_float(__builtin_amdgcn_readfirstlane(__float_as_int(x)));
}
__device__ __forceinline__ float clamp01(float x) {
  return __builtin_amdgcn_fmed3f(x, 0.f, 1.f);   // single v_med3_f32
}

__global__ __launch_bounds__(1024) void markowitz_kernel(
    const float* __restrict__ rets, const float* __restrict__ cov,
    const float* __restrict__ gam,  const float* __restrict__ alp,
    float* __restrict__ out)
{
  __shared__ char smem[LDS_BYTES] __attribute__((aligned(16)));

  const int t    = threadIdx.x;        // 0..1023
  const int sb   = t >> 9;             // sample slot within block (0/1)
  const int ts   = t & 511;            // thread id within sample
  const int lane = t & 63;
  const int w8   = (t >> 6) & 7;       // wave 0..7 within sample
  const int lm   = lane & 15;          // column-within-tile owner index
  const int hq   = lane >> 4;          // row-subgroup index

  char* sm   = smem + sb * SAMPLE_BYTES;
  float* STG = (float*)sm;
  f16*   CH  = (f16*)(sm + OFF_CH);
  f16*   CL  = (f16*)(sm + OFF_CL);

  const int b = 2 * blockIdx.x + sb;
  const float g  = gam[b];
  const float aa = fabsf(alp[b]);
  const float* __restrict__ C = cov + (size_t)b * (NA * NA);

  // Row-publisher lanes: lm in [4*hq, 4*hq+4) -> rows 16*w8+lm, 16*(w8+8)+lm
  const bool mk = ((lm >> 2) == hq);
  const int  cw = lm & 3;

  // ===== Phase 1: Q = (gC)^T(gC) + |a|I, ~f32-exact via compensated f16 syrk =====
  // acc[ii][J][p] = Q[16*(w8+8ii) + 4*hq + p][16*J + lm]   (m89 C/D layout)
  f32x4 acc[2][16];
  #pragma unroll
  for (int i = 0; i < 2; ++i)
    #pragma unroll
    for (int j = 0; j < 16; ++j)
      acc[i][j] = f32x4{0.f, 0.f, 0.f, 0.f};

  #pragma unroll 1
  for (int kb = 0; kb < 16; ++kb) {
    { // stage 16x256 f32 (gamma-folded), coalesced; 512 threads per sample
      const int kk = ts >> 5;          // 0..15
      const int ib = (ts & 31) << 3;   // 0,8,...,248
      const float* src = C + (size_t)(kb * 16 + kk) * NA + ib;
      float* dst = STG + kk * CSTR + ib;
      float4 c0 = *(const float4*)(src);
      float4 c1 = *(const float4*)(src + 4);
      *(float4*)(dst)     = make_float4(c0.x * g, c0.y * g, c0.z * g, c0.w * g);
      *(float4*)(dst + 4) = make_float4(c1.x * g, c1.y * g, c1.z * g, c1.w * g);
    }
    __syncthreads();
    { // transpose + hi/lo split into C^T tiles (256 cols x 16 k)
      const int ti = ts & 255;
      const int th = ts >> 8;          // k-half 0/1
      f16x8 vh, vlo;
      #pragma unroll
      for (int s2 = 0; s2 < 8; ++s2) {
        const float x = STG[(8 * th + s2) * CSTR + ti];
        const f16 h = (f16)x;
        vh[s2]  = h;
        vlo[s2] = (f16)(x - (float)h);   // exact residual
      }
      *(f16x8*)(CH + ti * TSTR + 8 * th) = vh;
      *(f16x8*)(CL + ti * TSTR + 8 * th) = vlo;
    }
    __syncthreads();
    // Q += H^T H + H^T L + L^T H  (L^T L ~ 2^-22, negligible)
    #pragma unroll
    for (int ii = 0; ii < 2; ++ii) {
      const int I = w8 + 8 * ii;
      const f16x4 aH = *(const f16x4*)(CH + (16 * I + lm) * TSTR + 4 * hq);
      const f16x4 aL = *(const f16x4*)(CL + (16 * I + lm) * TSTR + 4 * hq);
      #pragma unroll
      for (int J = 0; J < 16; ++J) {
        const f16x4 bH = *(const f16x4*)(CH + (16 * J + lm) * TSTR + 4 * hq);
        const f16x4 bL = *(const f16x4*)(CL + (16 * J + lm) * TSTR + 4 * hq);
        acc[ii][J] = __builtin_amdgcn_mfma_f32_16x16x16f16(aH, bH, acc[ii][J], 0, 0, 0);
        acc[ii][J] = __builtin_amdgcn_mfma_f32_16x16x16f16(aH, bL, acc[ii][J], 0, 0, 0);
        acc[ii][J] = __builtin_amdgcn_mfma_f32_16x16x16f16(aL, bH, acc[ii][J], 0, 0, 0);
      }
    }
  }

  // add |alpha| to the diagonal (row==col <=> J==I and lm==4*hq+p)
  #pragma unroll
  for (int J = 0; J < 16; ++J) {
    #pragma unroll
    for (int p = 0; p < 4; ++p) {
      if (J == w8     && lm == 4 * hq + p) acc[0][J][p] += aa;
      if (J == w8 + 8 && lm == 4 * hq + p) acc[1][J][p] += aa;
    }
  }

  // Per-lane column state (columns {16*j + lm}), all in registers.
  float rr[16];
  #pragma unroll
  for (int j = 0; j < 16; ++j) rr[j] = rets[b * NA + 16 * j + lm];

  float z[16];
  #pragma unroll
  for (int j = 0; j < 16; ++j) z[j] = 1.f;   // power-iteration b0 = ones

  // matvec from register z; after red16, all 16 lanes of a (w8,hq) group
  // hold y for rows {16*(w8+8ii)+4*hq+c}. Full-exec call sites only.
  auto matvec = [&](f32x4& y0, f32x4& y1) {
    y0 = f32x4{0.f, 0.f, 0.f, 0.f};
    y1 = f32x4{0.f, 0.f, 0.f, 0.f};
    #pragma unroll
    for (int J = 0; J < 16; ++J) {
      #pragma unroll
      for (int c = 0; c < 4; ++c) {
        y0[c] += acc[0][J][c] * z[J];
        y1[c] += acc[1][J][c] * z[J];
      }
    }
    #pragma unroll
    for (int c = 0; c < 4; ++c) { y0[c] = red16(y0[c]); y1[c] = red16(y1[c]); }
  };

  // publish y rows (only mk lanes): YY[16*w8+lm], YY[16*(w8+8)+lm]
  auto publish = [&](float* YYp, const f32x4& y0, const f32x4& y1) {
    if (mk) {
      const float ya = (cw == 0) ? y0[0] : (cw == 1) ? y0[1] : (cw == 2) ? y0[2] : y0[3];
      const float yb = (cw == 0) ? y1[0] : (cw == 1) ? y1[1] : (cw == 2) ? y1[2] : y1[3];
      YYp[16 * w8 + lm]       = ya;
      YYp[16 * (w8 + 8) + lm] = yb;
    }
  };

  // ===== Phase 2: power iteration + Rayleigh step size (1 barrier/iter) =====
  float step;
  {
    #pragma unroll 1
    for (int pi = 0; pi < POWER_ITERS; ++pi) {
      f32x4 y0, y1; matvec(y0, y1);
      float* YYp = (float*)(sm + ((pi & 1) ? OFF_YY1 : OFF_YY0));
      publish(YYp, y0, y1);
      __syncthreads();
      float yv[16];
      float nrm = 0.f;
      #pragma unroll
      for (int j = 0; j < 16; ++j) { yv[j] = YYp[16 * j + lm]; nrm += yv[j] * yv[j]; }
      nrm = rfl(red16(nrm));                  // uniform across all lanes/waves
      const float rb = 1.f / (sqrtf(nrm) + 1e-12f);
      #pragma unroll
      for (int j = 0; j < 16; ++j) z[j] = yv[j] * rb;   // bitwise-uniform copies
    }
    // lambda = b^T Q b  (POWER_ITERS is even -> buffer 0; prev iter used 1)
    f32x4 y0, y1; matvec(y0, y1);
    float* YYp = (float*)(sm + OFF_YY0);
    publish(YYp, y0, y1);
    __syncthreads();
    float lam = 0.f;
    #pragma unroll
    for (int j = 0; j < 16; ++j) lam += z[j] * YYp[16 * j + lm];
    lam = rfl(red16(lam));
    step = 1.f / (2.f * lam + 1e-6f);         // uniform
  }

  // ===== Phase 3: FISTA (1 barrier/iter, state in registers) =====
  float wo[16];
  #pragma unroll
  for (int j = 0; j < 16; ++j) { z[j] = 1.f / 256.f; wo[j] = 1.f / 256.f; }
  float tt = 1.f;
  float tauw = 1e30f;
  float kest = 32.f;     // persistent active-count (slope) estimate (uniform)

  #pragma unroll 1
  for (int it = 0; it < PGD_ITERS; ++it) {
    f32x4 y0, y1; matvec(y0, y1);
    // it=0 -> YY1 (lambda phase used YY0); alternates thereafter
    float* YYp = (float*)(sm + ((it & 1) ? OFF_YY0 : OFF_YY1));
    publish(YYp, y0, y1);
    __syncthreads();

    float v[16];
    #pragma unroll
    for (int j = 0; j < 16; ++j) {
      const float yv = YYp[16 * j + lm];
      v[j] = z[j] - step * (2.f * yv - rr[j]);  // uniform across duplicates
    }

    // Quarter-split projection: lane (lm,hq) evaluates columns
    // {16*(4hq+c)+lm, c=0..3} -> each wave's 64 lanes cover all 256 exactly
    // once. Reduce: 6 DPP + readlane(63) -> scalar; ALL bracket/secant logic
    // on the scalar pipe. Zero DS ops. Bracket [max(v)-1, max(v)].
    const float vq0 = (hq == 0) ? v[0] : (hq == 1) ? v[4]  : (hq == 2) ? v[8]  : v[12];
    const float vq1 = (hq == 0) ? v[1] : (hq == 1) ? v[5]  : (hq == 2) ? v[9]  : v[13];
    const float vq2 = (hq == 0) ? v[2] : (hq == 1) ? v[6]  : (hq == 2) ? v[10] : v[14];
    const float vq3 = (hq == 0) ? v[3] : (hq == 1) ? v[7]  : (hq == 2) ? v[11] : v[15];

    float lo = -1e30f, hi = 1e30f;
    float tau = tauw;
    float fprev = 0.f, tprev = 0.f;
    bool have = false;
    #pragma unroll 1
    for (int nit = 0; nit < 16; ++nit) {
      float sp = clamp01(vq0 - tau) + clamp01(vq1 - tau)
               + clamp01(vq2 - tau) + clamp01(vq3 - tau);
      const float s = redwave_add(sp);        // uniform scalar
      if (nit == 0) {
        const float pm = redwave_max(fmaxf(fmaxf(vq0, vq1), fmaxf(vq2, vq3)));
        lo = pm - 1.0f; hi = pm;
        if (!(tau > lo && tau < hi)) { tau = 0.5f * (lo + hi); continue; }
      }
      const float f = s - 1.f;
      if (fabsf(f) <= 1e-5f) break;
      if (f > 0.f) lo = tau; else hi = tau;
      if (hi - lo < 1e-7f) break;
      float kc = have ? ((f - fprev) / (tprev - tau)) : kest;  // secant slope
      if (!(kc > 0.5f)) kc = kest;            // plateau / first-eval fallback
      const float tn = tau + f / kc;
      fprev = f; tprev = tau; have = true;
      kest = fmaxf(kc, 1.f);
      const float tc = (tn > lo && tn < hi) ? tn : 0.5f * (lo + hi);
      if (tc == tau) break;                   // numerical fixed point
      tau = tc;
    }
    tauw = tau;

    const float tnew = 0.5f * (1.f + sqrtf(1.f + 4.f * tt * tt));
    const float coef = (tt - 1.f) / tnew;
    #pragma unroll
    for (int j = 0; j < 16; ++j) {
      const float wn = clamp01(v[j] - tau);
      z[j]  = wn + coef * (wn - wo[j]);
      wo[j] = wn;
    }
    tt = tnew;
  }

  // Output f32; each sample's wave 0, hq=0 subgroup holds every column once.
  if (w8 == 0 && lane < 16) {
    #pragma unroll
    for (int j = 0; j < 16; ++j) out[(size_t)b * NA + 16 * j + lane] = wo[j];
  }
}

extern "C" void kernel_launch(void* const* d_in, const int* in_sizes, int n_in,
                              void* d_out, int out_size, void* d_ws, size_t ws_size,
                              hipStream_t stream) {
  (void)in_sizes; (void)n_in; (void)out_size; (void)d_ws; (void)ws_size;
  const float* rets = (const float*)d_in[0];
  const float* cov  = (const float*)d_in[1];
  const float* gam  = (const float*)d_in[2];
  const float* alp  = (const float*)d_in[3];
  float* out = (float*)d_out;
  hipLaunchKernelGGL(markowitz_kernel, dim3(NS / 2), dim3(1024), 0, stream,
                     rets, cov, gam, alp, out);
}

// Round 12
// 2858.472 us; speedup vs baseline: 2.3345x; 2.3345x over previous
//
#include <hip/hip_runtime.h>

#define NS 512
#define NA 256
#define PGD_ITERS 300
#define POWER_ITERS 30

typedef _Float16 f16;
typedef __attribute__((ext_vector_type(4))) _Float16 f16x4;
typedef __attribute__((ext_vector_type(4))) float f32x4;

// LDS layout (bytes), one sample per block. Total 43,264 B.
#define CSTR 260            // f32 staging row stride (elems)
#define TSTR 24             // f16 C^T tile row stride (elems) = 48 B
#define OFF_CH  16640       // STG: 16*260*4
#define OFF_CL  28928       // CH:  256*24*2
#define OFF_YY0 41216       // CL:  256*24*2
#define OFF_YY1 42240       // YY0: 256 f32
#define LDS_BYTES 43264     // YY1: 256 f32

// ---- cross-lane primitives (VALU DPP; zero DS-pipe traffic) ----
// SAFETY: all call sites have FULL exec; control flow around them is
// wave-uniform (branches on readlane/readfirstlane scalars only).
template<int CTRL>
__device__ __forceinline__ float dpp_add(float x) {
  const int r = __builtin_amdgcn_update_dpp(0, __float_as_int(x), CTRL, 0xF, 0xF, true);
  return x + __int_as_float(r);
}
template<int CTRL>
__device__ __forceinline__ float dpp_max(float x) {
  const int r = __builtin_amdgcn_update_dpp(0, __float_as_int(x), CTRL, 0xF, 0xF, true);
  return fmaxf(x, __int_as_float(r));
}
// 16-lane-row sum via rotation doubling: every lane gets its row's total
__device__ __forceinline__ float red16(float x) {
  x = dpp_add<0x121>(x);  // row_ror:1
  x = dpp_add<0x122>(x);  // row_ror:2
  x = dpp_add<0x124>(x);  // row_ror:4
  x = dpp_add<0x128>(x);  // row_ror:8
  return x;
}
// full-wave64 sum -> uniform scalar (row sums, then bcast15/31, lane63)
__device__ __forceinline__ float redwave_add(float x) {
  x = red16(x);
  {
    const int r = __builtin_amdgcn_update_dpp(0, __float_as_int(x), 0x142, 0xA, 0xF, true);
    x += __int_as_float(r);
  }
  {
    const int r = __builtin_amdgcn_update_dpp(0, __float_as_int(x), 0x143, 0xC, 0xF, true);
    x += __int_as_float(r);
  }
  return __int_as_float(__builtin_amdgcn_readlane(__float_as_int(x), 63));
}
__device__ __forceinline__ float redwave_max(float x) {
  x = dpp_max<0x121>(x);
  x = dpp_max<0x122>(x);
  x = dpp_max<0x124>(x);
  x = dpp_max<0x128>(x);
  { // old=x for masked rows -> fmax(x,x)=x (safe for negatives)
    const int r = __builtin_amdgcn_update_dpp(__float_as_int(x), __float_as_int(x), 0x142, 0xA, 0xF, false);
    x = fmaxf(x, __int_as_float(r));
  }
  {
    const int r = __builtin_amdgcn_update_dpp(__float_as_int(x), __float_as_int(x), 0x143, 0xC, 0xF, false);
    x = fmaxf(x, __int_as_float(r));
  }
  return __int_as_float(__builtin_amdgcn_readlane(__float_as_int(x), 63));
}
__device__ __forceinline__ float rfl(float x) {
  return __int_as_float(__builtin_amdgcn_readfirstlane(__float_as_int(x)));
}
__device__ __forceinline__ float clamp01(float x) {
  return __builtin_amdgcn_fmed3f(x, 0.f, 1.f);   // single v_med3_f32
}

__global__ __launch_bounds__(1024) void markowitz_kernel(
    const float* __restrict__ rets, const float* __restrict__ cov,
    const float* __restrict__ gam,  const float* __restrict__ alp,
    float* __restrict__ out)
{
  __shared__ char smem[LDS_BYTES] __attribute__((aligned(16)));
  float* STG = (float*)smem;
  f16*   CH  = (f16*)(smem + OFF_CH);
  f16*   CL  = (f16*)(smem + OFF_CL);

  const int t    = threadIdx.x;        // 0..1023
  const int lane = t & 63;
  const int w16  = t >> 6;             // wave 0..15 (owns row-tile I = w16)
  const int lm   = lane & 15;          // column-within-tile owner index
  const int hq   = lane >> 4;          // row-subgroup index

  const int b = blockIdx.x;
  const float g  = gam[b];
  const float aa = fabsf(alp[b]);
  const float* __restrict__ C = cov + (size_t)b * (NA * NA);

  // Row-publisher lanes: lm in [4*hq, 4*hq+4) -> row 16*w16+lm
  const bool mk = ((lm >> 2) == hq);
  const int  cw = lm & 3;

  // ===== Phase 1: Q = (gC)^T(gC) + |a|I via compensated f16 syrk =====
  // acc[J][p] = Q[16*w16 + 4*hq + p][16*J + lm]   (m89 C/D layout)
  f32x4 acc[16];
  #pragma unroll
  for (int j = 0; j < 16; ++j) acc[j] = f32x4{0.f, 0.f, 0.f, 0.f};

  #pragma unroll 1
  for (int kb = 0; kb < 16; ++kb) {
    { // stage 16x256 f32 (gamma-folded), coalesced: 1 float4/thread
      const int kk = t >> 6;           // 0..15
      const int ib = (t & 63) << 2;    // 0,4,...,252
      float4 cv = *(const float4*)(C + (size_t)(kb * 16 + kk) * NA + ib);
      *(float4*)(STG + kk * CSTR + ib) =
          make_float4(cv.x * g, cv.y * g, cv.z * g, cv.w * g);
    }
    __syncthreads();
    { // transpose + hi/lo split: thread (ti, th) handles k = 4*th..4*th+3
      const int ti = t & 255;
      const int th = t >> 8;           // 0..3
      f16x4 vh, vlo;
      #pragma unroll
      for (int s2 = 0; s2 < 4; ++s2) {
        const float x = STG[(4 * th + s2) * CSTR + ti];
        const f16 h = (f16)x;
        vh[s2]  = h;
        vlo[s2] = (f16)(x - (float)h);   // exact residual
      }
      *(f16x4*)(CH + ti * TSTR + 4 * th) = vh;   // 8B aligned
      *(f16x4*)(CL + ti * TSTR + 4 * th) = vlo;
    }
    __syncthreads();
    // Q += H^T H + H^T L + L^T H  (L^T L ~ 2^-22, negligible)
    const f16x4 aH = *(const f16x4*)(CH + (16 * w16 + lm) * TSTR + 4 * hq);
    const f16x4 aL = *(const f16x4*)(CL + (16 * w16 + lm) * TSTR + 4 * hq);
    #pragma unroll
    for (int J = 0; J < 16; ++J) {
      const f16x4 bH = *(const f16x4*)(CH + (16 * J + lm) * TSTR + 4 * hq);
      const f16x4 bL = *(const f16x4*)(CL + (16 * J + lm) * TSTR + 4 * hq);
      acc[J] = __builtin_amdgcn_mfma_f32_16x16x16f16(aH, bH, acc[J], 0, 0, 0);
      acc[J] = __builtin_amdgcn_mfma_f32_16x16x16f16(aH, bL, acc[J], 0, 0, 0);
      acc[J] = __builtin_amdgcn_mfma_f32_16x16x16f16(aL, bH, acc[J], 0, 0, 0);
    }
  }

  // add |alpha| to the diagonal (row==col <=> J==w16 and lm==4*hq+p)
  #pragma unroll
  for (int J = 0; J < 16; ++J) {
    #pragma unroll
    for (int p = 0; p < 4; ++p) {
      if (J == w16 && lm == 4 * hq + p) acc[J][p] += aa;
    }
  }

  // Per-lane column state z (columns {16*j + lm}); v aliases z in FISTA.
  float z[16];
  #pragma unroll
  for (int j = 0; j < 16; ++j) z[j] = 1.f;   // power-iteration b0 = ones

  // matvec: y[c] = row (16*w16+4*hq+c) of Q*z after red16. Full-exec only.
  auto matvec = [&](f32x4& y) {
    y = f32x4{0.f, 0.f, 0.f, 0.f};
    #pragma unroll
    for (int J = 0; J < 16; ++J) {
      #pragma unroll
      for (int c = 0; c < 4; ++c) y[c] += acc[J][c] * z[J];
    }
    #pragma unroll
    for (int c = 0; c < 4; ++c) y[c] = red16(y[c]);
  };
  auto publish = [&](float* YYp, const f32x4& y) {
    if (mk) {
      const float yv = (cw == 0) ? y[0] : (cw == 1) ? y[1] : (cw == 2) ? y[2] : y[3];
      YYp[16 * w16 + lm] = yv;
    }
  };

  // ===== Phase 2: power iteration + Rayleigh step (1 barrier/iter) =====
  float step;
  {
    #pragma unroll 1
    for (int pi = 0; pi < POWER_ITERS; ++pi) {
      f32x4 y; matvec(y);
      float* YYp = (float*)(smem + ((pi & 1) ? OFF_YY1 : OFF_YY0));
      publish(YYp, y);
      __syncthreads();
      float nrm = 0.f;
      #pragma unroll
      for (int j = 0; j < 16; ++j) {
        const float tv = YYp[16 * j + lm];
        nrm += tv * tv;
        z[j] = tv;
      }
      nrm = rfl(red16(nrm));                  // uniform across all lanes
      const float rb = 1.f / (sqrtf(nrm) + 1e-12f);
      #pragma unroll
      for (int j = 0; j < 16; ++j) z[j] *= rb;
    }
    f32x4 y; matvec(y);                       // lambda = b^T Q b
    float* YYp = (float*)(smem + OFF_YY0);    // POWER_ITERS even -> prev=YY1
    publish(YYp, y);
    __syncthreads();
    float lam = 0.f;
    #pragma unroll
    for (int j = 0; j < 16; ++j) lam += z[j] * YYp[16 * j + lm];
    lam = rfl(red16(lam));
    step = 1.f / (2.f * lam + 1e-6f);         // uniform
  }

  // ===== Phase 3: FISTA (1 barrier/iter; z/wo in regs, v aliases z) =====
  float wo[16];
  #pragma unroll
  for (int j = 0; j < 16; ++j) { z[j] = 1.f / 256.f; wo[j] = 1.f / 256.f; }
  float tt = 1.f;
  float tauw = 1e30f;
  float kest = 32.f;
  const float* rp = rets + b * NA + lm;       // rr re-read per iter (L1-hot)

  #pragma unroll 1
  for (int it = 0; it < PGD_ITERS; ++it) {
    f32x4 y; matvec(y);
    float* YYp = (float*)(smem + ((it & 1) ? OFF_YY0 : OFF_YY1));
    publish(YYp, y);
    __syncthreads();

    // v = z - step*(2y - r), stored in place of z
    #pragma unroll
    for (int j = 0; j < 16; ++j) {
      const float yv = YYp[16 * j + lm];
      z[j] = z[j] - step * (2.f * yv - rp[16 * j]);
    }

    // Quarter-split projection: lane (lm,hq) evaluates cols {16*(4hq+c)+lm}
    // -> 64 lanes of any wave cover all 256 once. Reduce: 6 DPP +
    // readlane(63); all bracket/secant logic on uniform scalars. Zero DS.
    const float vq0 = (hq == 0) ? z[0] : (hq == 1) ? z[4]  : (hq == 2) ? z[8]  : z[12];
    const float vq1 = (hq == 0) ? z[1] : (hq == 1) ? z[5]  : (hq == 2) ? z[9]  : z[13];
    const float vq2 = (hq == 0) ? z[2] : (hq == 1) ? z[6]  : (hq == 2) ? z[10] : z[14];
    const float vq3 = (hq == 0) ? z[3] : (hq == 1) ? z[7]  : (hq == 2) ? z[11] : z[15];

    float lo = -1e30f, hi = 1e30f;
    float tau = tauw;
    float fprev = 0.f, tprev = 0.f;
    bool have = false;
    #pragma unroll 1
    for (int nit = 0; nit < 16; ++nit) {
      float sp = clamp01(vq0 - tau) + clamp01(vq1 - tau)
               + clamp01(vq2 - tau) + clamp01(vq3 - tau);
      const float s = redwave_add(sp);        // uniform scalar
      if (nit == 0) {
        const float pm = redwave_max(fmaxf(fmaxf(vq0, vq1), fmaxf(vq2, vq3)));
        lo = pm - 1.0f; hi = pm;              // root always in [max-1, max]
        if (!(tau > lo && tau < hi)) { tau = 0.5f * (lo + hi); continue; }
      }
      const float f = s - 1.f;
      if (fabsf(f) <= 1e-5f) break;
      if (f > 0.f) lo = tau; else hi = tau;
      if (hi - lo < 1e-7f) break;
      float kc = have ? ((f - fprev) / (tprev - tau)) : kest;  // secant slope
      if (!(kc > 0.5f)) kc = kest;
      const float tn = tau + f / kc;
      fprev = f; tprev = tau; have = true;
      kest = fmaxf(kc, 1.f);
      const float tc = (tn > lo && tn < hi) ? tn : 0.5f * (lo + hi);
      if (tc == tau) break;                   // numerical fixed point
      tau = tc;
    }
    tauw = tau;

    const float tnew = 0.5f * (1.f + sqrtf(1.f + 4.f * tt * tt));
    const float coef = (tt - 1.f) / tnew;
    #pragma unroll
    for (int j = 0; j < 16; ++j) {
      const float wn = clamp01(z[j] - tau);   // z holds v here
      z[j]  = wn + coef * (wn - wo[j]);
      wo[j] = wn;
    }
    tt = tnew;
  }

  // Output f32; wave 0, hq=0 lanes hold every column once.
  if (w16 == 0 && lane < 16) {
    #pragma unroll
    for (int j = 0; j < 16; ++j) out[(size_t)b * NA + 16 * j + lane] = wo[j];
  }
}

extern "C" void kernel_launch(void* const* d_in, const int* in_sizes, int n_in,
                              void* d_out, int out_size, void* d_ws, size_t ws_size,
                              hipStream_t stream) {
  (void)in_sizes; (void)n_in; (void)out_size; (void)d_ws; (void)ws_size;
  const float* rets = (const float*)d_in[0];
  const float* cov  = (const float*)d_in[1];
  const float* gam  = (const float*)d_in[2];
  const float* alp  = (const float*)d_in[3];
  float* out = (float*)d_out;
  hipLaunchKernelGGL(markowitz_kernel, dim3(NS), dim3(1024), 0, stream,
                     rets, cov, gam, alp, out);
}

// Round 14
// 1750.639 us; speedup vs baseline: 3.8117x; 1.6328x over previous
//
#include <hip/hip_runtime.h>

#define NS 512
#define NA 256
#define PGD_ITERS 300
#define POWER_ITERS 30

typedef _Float16 f16;
typedef __attribute__((ext_vector_type(4))) _Float16 f16x4;
typedef __attribute__((ext_vector_type(8))) _Float16 f16x8;
typedef __attribute__((ext_vector_type(4))) float f32x4;

// LDS layout (bytes). STG/CH/CL live only during the syrk; YY0/YY1 double-
// buffer the y-exchange.
#define CSTR 260            // f32 staging row stride (elems)
#define TSTR 24             // f16 C^T tile row stride (elems) = 48 B
#define OFF_CH  16640       // STG: 16*260*4
#define OFF_CL  28928       // CH:  256*24*2
#define OFF_YY0 41216       // CL:  256*24*2
#define OFF_YY1 42240       // YY0: 256 f32
#define LDS_BYTES 43264     // YY1: 256 f32

// ---- cross-lane primitives (VALU DPP; zero DS-pipe traffic) ----
// SAFETY: all call sites have FULL exec; all control flow around them is
// wave-uniform (branches only on readlane/readfirstlane scalars).
template<int CTRL>
__device__ __forceinline__ float dpp_add(float x) {
  const int r = __builtin_amdgcn_update_dpp(0, __float_as_int(x), CTRL, 0xF, 0xF, true);
  return x + __int_as_float(r);
}
template<int CTRL>
__device__ __forceinline__ float dpp_max(float x) {
  const int r = __builtin_amdgcn_update_dpp(0, __float_as_int(x), CTRL, 0xF, 0xF, true);
  return fmaxf(x, __int_as_float(r));
}
// 16-lane-row sum via rotation doubling: every lane gets its row's total
__device__ __forceinline__ float red16(float x) {
  x = dpp_add<0x121>(x);  // row_ror:1
  x = dpp_add<0x122>(x);  // row_ror:2
  x = dpp_add<0x124>(x);  // row_ror:4
  x = dpp_add<0x128>(x);  // row_ror:8
  return x;
}
// full-wave64 sum -> uniform scalar (row sums, then bcast15/31, lane63)
__device__ __forceinline__ float redwave_add(float x) {
  x = red16(x);
  {
    const int r = __builtin_amdgcn_update_dpp(0, __float_as_int(x), 0x142, 0xA, 0xF, true);
    x += __int_as_float(r);
  }
  {
    const int r = __builtin_amdgcn_update_dpp(0, __float_as_int(x), 0x143, 0xC, 0xF, true);
    x += __int_as_float(r);
  }
  return __int_as_float(__builtin_amdgcn_readlane(__float_as_int(x), 63));
}
__device__ __forceinline__ float redwave_max(float x) {
  x = dpp_max<0x121>(x);
  x = dpp_max<0x122>(x);
  x = dpp_max<0x124>(x);
  x = dpp_max<0x128>(x);
  { // old=x for masked rows -> fmax(x,x)=x (safe for negatives)
    const int r = __builtin_amdgcn_update_dpp(__float_as_int(x), __float_as_int(x), 0x142, 0xA, 0xF, false);
    x = fmaxf(x, __int_as_float(r));
  }
  {
    const int r = __builtin_amdgcn_update_dpp(__float_as_int(x), __float_as_int(x), 0x143, 0xC, 0xF, false);
    x = fmaxf(x, __int_as_float(r));
  }
  return __int_as_float(__builtin_amdgcn_readlane(__float_as_int(x), 63));
}
__device__ __forceinline__ float rfl(float x) {
  return __int_as_float(__builtin_amdgcn_readfirstlane(__float_as_int(x)));
}
__device__ __forceinline__ float clamp01(float x) {
  return __builtin_amdgcn_fmed3f(x, 0.f, 1.f);   // single v_med3_f32
}

__global__ __launch_bounds__(512) void markowitz_kernel(
    const float* __restrict__ rets, const float* __restrict__ cov,
    const float* __restrict__ gam,  const float* __restrict__ alp,
    float* __restrict__ out)
{
  __shared__ char smem[LDS_BYTES] __attribute__((aligned(16)));
  float* STG = (float*)smem;
  f16*   CH  = (f16*)(smem + OFF_CH);
  f16*   CL  = (f16*)(smem + OFF_CL);

  const int t    = threadIdx.x;
  const int lane = t & 63;
  const int w8   = t >> 6;          // wave 0..7
  const int lm   = lane & 15;       // column-within-tile owner index
  const int hq   = lane >> 4;       // row-subgroup index

  const int b = blockIdx.x;
  const float g  = gam[b];
  const float aa = fabsf(alp[b]);
  const float* __restrict__ C = cov + (size_t)b * (NA * NA);

  // Row-publisher lanes: lm in [4*hq, 4*hq+4) -> rows 16*w8+lm, 16*(w8+8)+lm
  const bool mk = ((lm >> 2) == hq);
  const int  cw = lm & 3;

  // ===== Phase 1: Q = (gC)^T(gC) + |a|I via compensated f16 syrk =====
  // acc[ii][J][p] = Q[16*(w8+8ii) + 4*hq + p][16*J + lm]   (m89 C/D layout)
  f32x4 acc[2][16];
  #pragma unroll
  for (int i = 0; i < 2; ++i)
    #pragma unroll
    for (int j = 0; j < 16; ++j)
      acc[i][j] = f32x4{0.f, 0.f, 0.f, 0.f};

  #pragma unroll 1
  for (int kb = 0; kb < 16; ++kb) {
    { // stage 16x256 f32 (gamma-folded), coalesced
      const int kk = t >> 5;          // 0..15
      const int ib = (t & 31) << 3;   // 0,8,...,248
      const float* src = C + (size_t)(kb * 16 + kk) * NA + ib;
      float* dst = STG + kk * CSTR + ib;
      float4 c0 = *(const float4*)(src);
      float4 c1 = *(const float4*)(src + 4);
      *(float4*)(dst)     = make_float4(c0.x * g, c0.y * g, c0.z * g, c0.w * g);
      *(float4*)(dst + 4) = make_float4(c1.x * g, c1.y * g, c1.z * g, c1.w * g);
    }
    __syncthreads();
    { // transpose + hi/lo split into C^T tiles (256 cols x 16 k)
      const int ti = t & 255;
      const int th = t >> 8;          // k-half 0/1
      f16x8 vh, vlo;
      #pragma unroll
      for (int s2 = 0; s2 < 8; ++s2) {
        const float x = STG[(8 * th + s2) * CSTR + ti];
        const f16 h = (f16)x;
        vh[s2]  = h;
        vlo[s2] = (f16)(x - (float)h);   // exact residual
      }
      *(f16x8*)(CH + ti * TSTR + 8 * th) = vh;
      *(f16x8*)(CL + ti * TSTR + 8 * th) = vlo;
    }
    __syncthreads();
    // Q += H^T H + H^T L + L^T H  (L^T L ~ 2^-22, negligible)
    #pragma unroll
    for (int ii = 0; ii < 2; ++ii) {
      const int I = w8 + 8 * ii;
      const f16x4 aH = *(const f16x4*)(CH + (16 * I + lm) * TSTR + 4 * hq);
      const f16x4 aL = *(const f16x4*)(CL + (16 * I + lm) * TSTR + 4 * hq);
      #pragma unroll
      for (int J = 0; J < 16; ++J) {
        const f16x4 bH = *(const f16x4*)(CH + (16 * J + lm) * TSTR + 4 * hq);
        const f16x4 bL = *(const f16x4*)(CL + (16 * J + lm) * TSTR + 4 * hq);
        acc[ii][J] = __builtin_amdgcn_mfma_f32_16x16x16f16(aH, bH, acc[ii][J], 0, 0, 0);
        acc[ii][J] = __builtin_amdgcn_mfma_f32_16x16x16f16(aH, bL, acc[ii][J], 0, 0, 0);
        acc[ii][J] = __builtin_amdgcn_mfma_f32_16x16x16f16(aL, bH, acc[ii][J], 0, 0, 0);
      }
    }
  }

  // add |alpha| to the diagonal (row==col <=> J==I and lm==4*hq+p)
  #pragma unroll
  for (int J = 0; J < 16; ++J) {
    #pragma unroll
    for (int p = 0; p < 4; ++p) {
      if (J == w8     && lm == 4 * hq + p) acc[0][J][p] += aa;
      if (J == w8 + 8 && lm == 4 * hq + p) acc[1][J][p] += aa;
    }
  }

  // Per-lane column state (columns {16*j + lm}), all in registers.
  float rr[16];
  #pragma unroll
  for (int j = 0; j < 16; ++j) rr[j] = rets[b * NA + 16 * j + lm];

  float z[16];
  #pragma unroll
  for (int j = 0; j < 16; ++j) z[j] = 1.f;   // power-iteration b0 = ones

  // matvec from register z; f32x4 vector FMAs -> v_pk_fma_f32 pairs.
  auto matvec = [&](f32x4& y0, f32x4& y1) {
    y0 = f32x4{0.f, 0.f, 0.f, 0.f};
    y1 = f32x4{0.f, 0.f, 0.f, 0.f};
    #pragma unroll
    for (int J = 0; J < 16; ++J) {
      y0 += acc[0][J] * z[J];
      y1 += acc[1][J] * z[J];
    }
    #pragma unroll
    for (int c = 0; c < 4; ++c) { y0[c] = red16(y0[c]); y1[c] = red16(y1[c]); }
  };

  // publish y rows (only mk lanes): YY[16*w8+lm], YY[16*(w8+8)+lm]
  auto publish = [&](float* YYp, const f32x4& y0, const f32x4& y1) {
    if (mk) {
      const float ya = (cw == 0) ? y0[0] : (cw == 1) ? y0[1] : (cw == 2) ? y0[2] : y0[3];
      const float yb = (cw == 0) ? y1[0] : (cw == 1) ? y1[1] : (cw == 2) ? y1[2] : y1[3];
      YYp[16 * w8 + lm]       = ya;
      YYp[16 * (w8 + 8) + lm] = yb;
    }
  };

  // ===== Phase 2: power iteration + Rayleigh step (1 barrier/iter) =====
  float step;
  {
    #pragma unroll 1
    for (int pi = 0; pi < POWER_ITERS; ++pi) {
      f32x4 y0, y1; matvec(y0, y1);
      float* YYp = (float*)(smem + ((pi & 1) ? OFF_YY1 : OFF_YY0));
      publish(YYp, y0, y1);
      __syncthreads();
      float nrm = 0.f;
      #pragma unroll
      for (int j = 0; j < 16; ++j) {
        const float tv = YYp[16 * j + lm];
        nrm += tv * tv;
        z[j] = tv;
      }
      nrm = rfl(red16(nrm));                  // uniform
      const float rb = 1.f / (sqrtf(nrm) + 1e-12f);
      #pragma unroll
      for (int j = 0; j < 16; ++j) z[j] *= rb;
    }
    f32x4 y0, y1; matvec(y0, y1);             // lambda = b^T Q b
    float* YYp = (float*)(smem + OFF_YY0);
    publish(YYp, y0, y1);
    __syncthreads();
    float lam = 0.f;
    #pragma unroll
    for (int j = 0; j < 16; ++j) lam += z[j] * YYp[16 * j + lm];
    lam = rfl(red16(lam));
    step = 1.f / (2.f * lam + 1e-6f);         // uniform
  }

  // ===== Phase 3: FISTA (1 barrier/iter; R12-verified projection) =====
  float wo[16];
  #pragma unroll
  for (int j = 0; j < 16; ++j) { z[j] = 1.f / 256.f; wo[j] = 1.f / 256.f; }
  float tt = 1.f;
  float tauw = 1e30f;
  float kest = 32.f;

  #pragma unroll 1
  for (int it = 0; it < PGD_ITERS; ++it) {
    f32x4 y0, y1; matvec(y0, y1);
    float* YYp = (float*)(smem + ((it & 1) ? OFF_YY0 : OFF_YY1));
    publish(YYp, y0, y1);
    __syncthreads();

    float v[16];
    #pragma unroll
    for (int j = 0; j < 16; ++j) {
      const float yv = YYp[16 * j + lm];
      v[j] = z[j] - step * (2.f * yv - rr[j]);
    }

    // Quarter-split projection: lane (lm,hq) evaluates cols {16*(4hq+c)+lm}
    // -> 64 lanes cover all 256 once. Reduce: 6 DPP + readlane(63) -> SGPR;
    // ALL bracket/secant control on uniform scalars with early exit
    // (verified correct in R10/R12). Zero DS ops on this path.
    const float vq0 = (hq == 0) ? v[0] : (hq == 1) ? v[4]  : (hq == 2) ? v[8]  : v[12];
    const float vq1 = (hq == 0) ? v[1] : (hq == 1) ? v[5]  : (hq == 2) ? v[9]  : v[13];
    const float vq2 = (hq == 0) ? v[2] : (hq == 1) ? v[6]  : (hq == 2) ? v[10] : v[14];
    const float vq3 = (hq == 0) ? v[3] : (hq == 1) ? v[7]  : (hq == 2) ? v[11] : v[15];

    float lo = -1e30f, hi = 1e30f;
    float tau = tauw;
    float fprev = 0.f, tprev = 0.f;
    bool have = false;
    #pragma unroll 1
    for (int nit = 0; nit < 16; ++nit) {
      float sp = clamp01(vq0 - tau) + clamp01(vq1 - tau)
               + clamp01(vq2 - tau) + clamp01(vq3 - tau);
      const float s = redwave_add(sp);        // uniform scalar
      if (nit == 0) {
        const float pm = redwave_max(fmaxf(fmaxf(vq0, vq1), fmaxf(vq2, vq3)));
        lo = pm - 1.0f; hi = pm;              // root always in [max-1, max]
        if (!(tau > lo && tau < hi)) { tau = 0.5f * (lo + hi); continue; }
      }
      const float f = s - 1.f;
      if (fabsf(f) <= 1e-5f) break;
      if (f > 0.f) lo = tau; else hi = tau;
      if (hi - lo < 1e-7f) break;
      float kc = have ? ((f - fprev) / (tprev - tau)) : kest;  // secant slope
      if (!(kc > 0.5f)) kc = kest;
      const float tn = tau + f / kc;
      fprev = f; tprev = tau; have = true;
      kest = fmaxf(kc, 1.f);
      const float tc = (tn > lo && tn < hi) ? tn : 0.5f * (lo + hi);
      if (tc == tau) break;                   // numerical fixed point
      tau = tc;
    }
    tauw = tau;

    const float tnew = 0.5f * (1.f + sqrtf(1.f + 4.f * tt * tt));
    const float coef = (tt - 1.f) / tnew;
    #pragma unroll
    for (int j = 0; j < 16; ++j) {
      const float wn = clamp01(v[j] - tau);
      z[j]  = wn + coef * (wn - wo[j]);
      wo[j] = wn;
    }
    tt = tnew;
  }

  // Output f32; wave 0, hq=0 lanes hold every column once.
  if (w8 == 0 && lane < 16) {
    #pragma unroll
    for (int j = 0; j < 16; ++j) out[(size_t)b * NA + 16 * j + lane] = wo[j];
  }
}

extern "C" void kernel_launch(void* const* d_in, const int* in_sizes, int n_in,
                              void* d_out, int out_size, void* d_ws, size_t ws_size,
                              hipStream_t stream) {
  (void)in_sizes; (void)n_in; (void)out_size; (void)d_ws; (void)ws_size;
  const float* rets = (const float*)d_in[0];
  const float* cov  = (const float*)d_in[1];
  const float* gam  = (const float*)d_in[2];
  const float* alp  = (const float*)d_in[3];
  float* out = (float*)d_out;
  hipLaunchKernelGGL(markowitz_kernel, dim3(NS), dim3(512), 0, stream,
                     rets, cov, gam, alp, out);
}

// Round 16
// 1725.446 us; speedup vs baseline: 3.8674x; 1.0146x over previous
//
#include <hip/hip_runtime.h>

#define NS 512
#define NA 256
#define PGD_ITERS 300
#define POWER_ITERS 30

typedef _Float16 f16;
typedef __attribute__((ext_vector_type(2))) _Float16 f16x2;
typedef __attribute__((ext_vector_type(2))) __fp16 fp16x2_raw;
typedef __attribute__((ext_vector_type(4))) _Float16 f16x4;
typedef __attribute__((ext_vector_type(8))) _Float16 f16x8;
typedef __attribute__((ext_vector_type(4))) float f32x4;

// LDS layout (bytes). STG/CH live only during the syrk; YY0/YY1 double-
// buffer the y-exchange; RR caches rets. DTMP (512 f32, diag partials)
// overlays YY0+YY1 before the iterative phases. Total 32,000 B -> two
// 8-wave blocks co-resident per CU (target: 4 waves/SIMD).
#define CSTR 260            // f32 staging row stride (elems)
#define TSTR 24             // f16 C^T tile row stride (elems) = 48 B
#define OFF_CH  16640       // STG: 16*260*4
#define OFF_YY0 28928       // CH:  256*24*2
#define OFF_YY1 29952
#define OFF_RR  30976
#define LDS_BYTES 32000

// ---- cross-lane primitives (VALU DPP; zero DS-pipe traffic) ----
// SAFETY: all call sites have FULL exec; branches only on wave-uniform
// scalars (readlane/readfirstlane results or wave-id comparisons).
template<int CTRL>
__device__ __forceinline__ float dpp_add(float x) {
  const int r = __builtin_amdgcn_update_dpp(0, __float_as_int(x), CTRL, 0xF, 0xF, true);
  return x + __int_as_float(r);
}
template<int CTRL>
__device__ __forceinline__ float dpp_max(float x) {
  const int r = __builtin_amdgcn_update_dpp(0, __float_as_int(x), CTRL, 0xF, 0xF, true);
  return fmaxf(x, __int_as_float(r));
}
__device__ __forceinline__ float red16(float x) {
  x = dpp_add<0x121>(x);  // row_ror:1
  x = dpp_add<0x122>(x);  // row_ror:2
  x = dpp_add<0x124>(x);  // row_ror:4
  x = dpp_add<0x128>(x);  // row_ror:8
  return x;
}
__device__ __forceinline__ float redwave_add(float x) {
  x = red16(x);
  {
    const int r = __builtin_amdgcn_update_dpp(0, __float_as_int(x), 0x142, 0xA, 0xF, true);
    x += __int_as_float(r);
  }
  {
    const int r = __builtin_amdgcn_update_dpp(0, __float_as_int(x), 0x143, 0xC, 0xF, true);
    x += __int_as_float(r);
  }
  return __int_as_float(__builtin_amdgcn_readlane(__float_as_int(x), 63));
}
__device__ __forceinline__ float redwave_max(float x) {
  x = dpp_max<0x121>(x);
  x = dpp_max<0x122>(x);
  x = dpp_max<0x124>(x);
  x = dpp_max<0x128>(x);
  {
    const int r = __builtin_amdgcn_update_dpp(__float_as_int(x), __float_as_int(x), 0x142, 0xA, 0xF, false);
    x = fmaxf(x, __int_as_float(r));
  }
  {
    const int r = __builtin_amdgcn_update_dpp(__float_as_int(x), __float_as_int(x), 0x143, 0xC, 0xF, false);
    x = fmaxf(x, __int_as_float(r));
  }
  return __int_as_float(__builtin_amdgcn_readlane(__float_as_int(x), 63));
}
__device__ __forceinline__ float rfl(float x) {
  return __int_as_float(__builtin_amdgcn_readfirstlane(__float_as_int(x)));
}
__device__ __forceinline__ float clamp01(float x) {
  return __builtin_amdgcn_fmed3f(x, 0.f, 1.f);
}
__device__ __forceinline__ f16x2 pk2(float a, float b) {
  return __builtin_bit_cast(f16x2, __builtin_amdgcn_cvt_pkrtz(a, b));
}
__device__ __forceinline__ float dot2f(f16x2 a, f16x2 b, float c) {
  return __builtin_amdgcn_fdot2(a, b, c, false);   // v_dot2_f32_f16
}

__global__ __launch_bounds__(512, 4) void markowitz_kernel(
    const float* __restrict__ rets, const float* __restrict__ cov,
    const float* __restrict__ gam,  const float* __restrict__ alp,
    float* __restrict__ out)
{
  __shared__ char smem[LDS_BYTES] __attribute__((aligned(16)));
  float* STG  = (float*)smem;
  f16*   CH   = (f16*)(smem + OFF_CH);
  float* DTMP = (float*)(smem + OFF_YY0);   // 512 f32 overlay (YY0+YY1)
  float* RRl  = (float*)(smem + OFF_RR);

  const int t    = threadIdx.x;
  const int lane = t & 63;
  const int w8   = t >> 6;          // wave 0..7
  const int lm   = lane & 15;       // column-within-tile owner index
  const int hq   = lane >> 4;       // row-subgroup index

  const int b = blockIdx.x;
  const float g  = gam[b];
  const float aa = fabsf(alp[b]);
  const float* __restrict__ C = cov + (size_t)b * (NA * NA);

  const bool mk = ((lm >> 2) == hq);
  const int  cw = lm & 3;

  // ===== Phase 1: Q = (gC)^T(gC), f16-packed registers + exact f32 diag =====
  // ah[ii][j2][c] packs Q[16*(w8+8ii)+4hq+c][16*(2j2)+lm | 16*(2j2+1)+lm]
  // as f16 pairs for v_dot2 (diag slots zeroed; exact diag added separately).
  f16x2 ah[2][8][4];
  float dacc = 0.f;                 // exact diag partial (pass 0 transpose)

  #pragma unroll
  for (int pass = 0; pass < 2; ++pass) {
    f32x4 acc1[16];
    #pragma unroll
    for (int j = 0; j < 16; ++j) acc1[j] = f32x4{0.f, 0.f, 0.f, 0.f};

    #pragma unroll 1
    for (int kb = 0; kb < 16; ++kb) {
      { // stage 16x256 f32 (gamma-folded), coalesced
        const int kk = t >> 5;
        const int ib = (t & 31) << 3;
        const float* src = C + (size_t)(kb * 16 + kk) * NA + ib;
        float* dst = STG + kk * CSTR + ib;
        float4 c0 = *(const float4*)(src);
        float4 c1 = *(const float4*)(src + 4);
        *(float4*)(dst)     = make_float4(c0.x * g, c0.y * g, c0.z * g, c0.w * g);
        *(float4*)(dst + 4) = make_float4(c1.x * g, c1.y * g, c1.z * g, c1.w * g);
      }
      __syncthreads();
      { // transpose to f16 C^T tile; pass 0 also accumulates exact diag
        const int ti = t & 255;
        const int th = t >> 8;       // k-half 0/1
        f16x8 vh;
        #pragma unroll
        for (int s2 = 0; s2 < 8; ++s2) {
          const float x = STG[(8 * th + s2) * CSTR + ti];
          if (pass == 0) dacc += x * x;
          vh[s2] = (f16)x;
        }
        *(f16x8*)(CH + ti * TSTR + 8 * th) = vh;
      }
      __syncthreads();
      const int I = w8 + 8 * pass;
      const f16x4 aH = *(const f16x4*)(CH + (16 * I + lm) * TSTR + 4 * hq);
      #pragma unroll
      for (int J = 0; J < 16; ++J) {
        const f16x4 bH = *(const f16x4*)(CH + (16 * J + lm) * TSTR + 4 * hq);
        acc1[J] = __builtin_amdgcn_mfma_f32_16x16x16f16(aH, bH, acc1[J], 0, 0, 0);
      }
    }
    // pack to f16 pairs; zero the diag slot (handled exactly via dgv)
    const int dj = w8 + 8 * pass;
    #pragma unroll
    for (int j2 = 0; j2 < 8; ++j2) {
      #pragma unroll
      for (int c = 0; c < 4; ++c) {
        float a0 = acc1[2 * j2][c];
        float a1 = acc1[2 * j2 + 1][c];
        if (2 * j2     == dj && lm == 4 * hq + c) a0 = 0.f;
        if (2 * j2 + 1 == dj && lm == 4 * hq + c) a1 = 0.f;
        ah[pass][j2][c] = pk2(a0, a1);
      }
    }
  }

  // exact diag sums + rets cache -> LDS
  {
    const int ti = t & 255;
    const int th = t >> 8;
    DTMP[th * 256 + ti] = dacc;
    if (t < 256) RRl[t] = rets[b * NA + t];
  }
  __syncthreads();
  float dg0 = 0.f, dg1 = 0.f;
  if (mk) {
    const int c0 = 16 * w8 + lm, c1 = 16 * (w8 + 8) + lm;
    dg0 = DTMP[c0] + DTMP[256 + c0] + aa;   // exact gamma^2*sum C^2 + |alpha|
    dg1 = DTMP[c1] + DTMP[256 + c1] + aa;
  }
  f32x4 dgv0, dgv1;
  #pragma unroll
  for (int p = 0; p < 4; ++p) {
    dgv0[p] = (lm == 4 * hq + p) ? dg0 : 0.f;
    dgv1[p] = (lm == 4 * hq + p) ? dg1 : 0.f;
  }
  __syncthreads();   // DTMP dead; YY0/YY1 safe to use

  float* const YY0 = (float*)(smem + OFF_YY0);
  float* const YY1 = (float*)(smem + OFF_YY1);

  float z[16];
  #pragma unroll
  for (int j = 0; j < 16; ++j) z[j] = 1.f;   // power b0 = ones

  // matvec: f16 dot2 over packed Q + exact f32 diag. Full-exec call sites.
  auto matvec = [&](f32x4& y0, f32x4& y1) {
    f16x2 zpk[8];
    float zd0 = 1.f, zd1 = 1.f;
    #pragma unroll
    for (int j2 = 0; j2 < 8; ++j2) {
      zpk[j2] = pk2(z[2 * j2], z[2 * j2 + 1]);
      if (2 * j2     == w8)     zd0 = z[2 * j2];
      if (2 * j2 + 1 == w8)     zd0 = z[2 * j2 + 1];
      if (2 * j2     == w8 + 8) zd1 = z[2 * j2];
      if (2 * j2 + 1 == w8 + 8) zd1 = z[2 * j2 + 1];
    }
    y0 = dgv0 * zd0;
    y1 = dgv1 * zd1;
    #pragma unroll
    for (int j2 = 0; j2 < 8; ++j2) {
      #pragma unroll
      for (int c = 0; c < 4; ++c) {
        y0[c] = dot2f(ah[0][j2][c], zpk[j2], y0[c]);
        y1[c] = dot2f(ah[1][j2][c], zpk[j2], y1[c]);
      }
    }
    #pragma unroll
    for (int c = 0; c < 4; ++c) { y0[c] = red16(y0[c]); y1[c] = red16(y1[c]); }
  };
  auto publish = [&](float* YYp, const f32x4& y0, const f32x4& y1) {
    if (mk) {
      const float ya = (cw == 0) ? y0[0] : (cw == 1) ? y0[1] : (cw == 2) ? y0[2] : y0[3];
      const float yb = (cw == 0) ? y1[0] : (cw == 1) ? y1[1] : (cw == 2) ? y1[2] : y1[3];
      YYp[16 * w8 + lm]       = ya;
      YYp[16 * (w8 + 8) + lm] = yb;
    }
  };

  // ===== Phase 2: power iteration + Rayleigh step (1 barrier/iter) =====
  float step;
  {
    #pragma unroll 1
    for (int pi = 0; pi < POWER_ITERS; ++pi) {
      f32x4 y0, y1; matvec(y0, y1);
      float* YYp = (pi & 1) ? YY1 : YY0;
      publish(YYp, y0, y1);
      __syncthreads();
      float nrm = 0.f;
      #pragma unroll
      for (int j = 0; j < 16; ++j) {
        const float tv = YYp[16 * j + lm];
        nrm += tv * tv;
        z[j] = tv;
      }
      nrm = rfl(red16(nrm));
      const float rb = 1.f / (sqrtf(nrm) + 1e-12f);
      #pragma unroll
      for (int j = 0; j < 16; ++j) z[j] *= rb;
    }
    f32x4 y0, y1; matvec(y0, y1);             // lambda = b^T Q b
    publish(YY0, y0, y1);
    __syncthreads();
    float lam = 0.f;
    #pragma unroll
    for (int j = 0; j < 16; ++j) lam += z[j] * YY0[16 * j + lm];
    lam = rfl(red16(lam));
    step = 1.f / (2.f * lam + 1e-6f);
  }

  // ===== Phase 3: FISTA (1 barrier/iter; R12/R14-verified projection) =====
  f16x2 wopk[8];
  #pragma unroll
  for (int j = 0; j < 16; ++j) z[j] = 1.f / 256.f;
  #pragma unroll
  for (int j2 = 0; j2 < 8; ++j2) wopk[j2] = pk2(1.f / 256.f, 1.f / 256.f);
  float tt = 1.f;
  float tauw = 1e30f;
  float kest = 32.f;

  #pragma unroll 1
  for (int it = 0; it < PGD_ITERS; ++it) {
    f32x4 y0, y1; matvec(y0, y1);
    float* YYp = (it & 1) ? YY0 : YY1;
    publish(YYp, y0, y1);
    __syncthreads();

    // v = z - step*(2y - r), stored in place of z
    #pragma unroll
    for (int j = 0; j < 16; ++j) {
      const float yv = YYp[16 * j + lm];
      z[j] = z[j] - step * (2.f * yv - RRl[16 * j + lm]);
    }

    // Quarter-split projection (verified R10/R12/R14): uniform-scalar
    // secant w/ early exit; 6 DPP + readlane per eval; zero DS ops.
    const float vq0 = (hq == 0) ? z[0] : (hq == 1) ? z[4]  : (hq == 2) ? z[8]  : z[12];
    const float vq1 = (hq == 0) ? z[1] : (hq == 1) ? z[5]  : (hq == 2) ? z[9]  : z[13];
    const float vq2 = (hq == 0) ? z[2] : (hq == 1) ? z[6]  : (hq == 2) ? z[10] : z[14];
    const float vq3 = (hq == 0) ? z[3] : (hq == 1) ? z[7]  : (hq == 2) ? z[11] : z[15];

    float lo = -1e30f, hi = 1e30f;
    float tau = tauw;
    float fprev = 0.f, tprev = 0.f;
    bool have = false;
    #pragma unroll 1
    for (int nit = 0; nit < 16; ++nit) {
      float sp = clamp01(vq0 - tau) + clamp01(vq1 - tau)
               + clamp01(vq2 - tau) + clamp01(vq3 - tau);
      const float s = redwave_add(sp);
      if (nit == 0) {
        const float pm = redwave_max(fmaxf(fmaxf(vq0, vq1), fmaxf(vq2, vq3)));
        lo = pm - 1.0f; hi = pm;              // root always in [max-1, max]
        if (!(tau > lo && tau < hi)) { tau = 0.5f * (lo + hi); continue; }
      }
      const float f = s - 1.f;
      if (fabsf(f) <= 1e-5f) break;
      if (f > 0.f) lo = tau; else hi = tau;
      if (hi - lo < 1e-7f) break;
      float kc = have ? ((f - fprev) / (tprev - tau)) : kest;
      if (!(kc > 0.5f)) kc = kest;
      const float tn = tau + f / kc;
      fprev = f; tprev = tau; have = true;
      kest = fmaxf(kc, 1.f);
      const float tc = (tn > lo && tn < hi) ? tn : 0.5f * (lo + hi);
      if (tc == tau) break;
      tau = tc;
    }
    tauw = tau;

    const float tnew = 0.5f * (1.f + sqrtf(1.f + 4.f * tt * tt));
    const float coef = (tt - 1.f) / tnew;
    const bool last = (it == PGD_ITERS - 1);
    #pragma unroll
    for (int j2 = 0; j2 < 8; ++j2) {
      const float wn0 = clamp01(z[2 * j2]     - tau);   // z holds v here
      const float wn1 = clamp01(z[2 * j2 + 1] - tau);
      const float wo0 = (float)wopk[j2][0];
      const float wo1 = (float)wopk[j2][1];
      z[2 * j2]     = wn0 + coef * (wn0 - wo0);
      z[2 * j2 + 1] = wn1 + coef * (wn1 - wo1);
      wopk[j2] = pk2(wn0, wn1);
      if (last && w8 == 0 && hq == 0) {       // f32-exact final write
        out[(size_t)b * NA + 16 * (2 * j2)     + lm] = wn0;
        out[(size_t)b * NA + 16 * (2 * j2 + 1) + lm] = wn1;
      }
    }
    tt = tnew;
  }
}

extern "C" void kernel_launch(void* const* d_in, const int* in_sizes, int n_in,
                              void* d_out, int out_size, void* d_ws, size_t ws_size,
                              hipStream_t stream) {
  (void)in_sizes; (void)n_in; (void)out_size; (void)d_ws; (void)ws_size;
  const float* rets = (const float*)d_in[0];
  const float* cov  = (const float*)d_in[1];
  const float* gam  = (const float*)d_in[2];
  const float* alp  = (const float*)d_in[3];
  float* out = (float*)d_out;
  hipLaunchKernelGGL(markowitz_kernel, dim3(NS), dim3(512), 0, stream,
                     rets, cov, gam, alp, out);
}

// Round 17
// 1547.550 us; speedup vs baseline: 4.3120x; 1.1150x over previous
//
#include <hip/hip_runtime.h>

#define NS 512
#define NA 256
#define PGD_ITERS 300
#define POWER_ITERS 30

typedef _Float16 f16;
typedef __attribute__((ext_vector_type(2))) _Float16 f16x2;
typedef __attribute__((ext_vector_type(4))) _Float16 f16x4;
typedef __attribute__((ext_vector_type(8))) _Float16 f16x8;
typedef __attribute__((ext_vector_type(4))) float f32x4;

// LDS layout (bytes). STG/CH live only during the syrk; YY0/YY1 double-
// buffer the y-exchange. DTMP (512 f32 diag partials) overlays YY0+YY1.
#define CSTR 260            // f32 staging row stride (elems)
#define TSTR 24             // f16 C^T tile row stride (elems) = 48 B
#define OFF_CH  16640       // STG: 16*260*4
#define OFF_YY0 28928       // CH:  256*24*2
#define OFF_YY1 29952
#define LDS_BYTES 30976

// ---- cross-lane primitives (VALU DPP; minimal DS-pipe traffic) ----
// SAFETY: all call sites have FULL exec; branches only on wave-uniform
// scalars (readlane/readfirstlane results or wave-id comparisons).
template<int CTRL>
__device__ __forceinline__ float dpp_add(float x) {
  const int r = __builtin_amdgcn_update_dpp(0, __float_as_int(x), CTRL, 0xF, 0xF, true);
  return x + __int_as_float(r);
}
template<int CTRL>
__device__ __forceinline__ float dpp_max(float x) {
  const int r = __builtin_amdgcn_update_dpp(0, __float_as_int(x), CTRL, 0xF, 0xF, true);
  return fmaxf(x, __int_as_float(r));
}
__device__ __forceinline__ float red16(float x) {
  x = dpp_add<0x121>(x);  // row_ror:1
  x = dpp_add<0x122>(x);  // row_ror:2
  x = dpp_add<0x124>(x);  // row_ror:4
  x = dpp_add<0x128>(x);  // row_ror:8
  return x;
}
__device__ __forceinline__ float redwave_add(float x) {
  x = red16(x);
  {
    const int r = __builtin_amdgcn_update_dpp(0, __float_as_int(x), 0x142, 0xA, 0xF, true);
    x += __int_as_float(r);
  }
  {
    const int r = __builtin_amdgcn_update_dpp(0, __float_as_int(x), 0x143, 0xC, 0xF, true);
    x += __int_as_float(r);
  }
  return __int_as_float(__builtin_amdgcn_readlane(__float_as_int(x), 63));
}
__device__ __forceinline__ float redwave_max(float x) {
  x = dpp_max<0x121>(x);
  x = dpp_max<0x122>(x);
  x = dpp_max<0x124>(x);
  x = dpp_max<0x128>(x);
  {
    const int r = __builtin_amdgcn_update_dpp(__float_as_int(x), __float_as_int(x), 0x142, 0xA, 0xF, false);
    x = fmaxf(x, __int_as_float(r));
  }
  {
    const int r = __builtin_amdgcn_update_dpp(__float_as_int(x), __float_as_int(x), 0x143, 0xC, 0xF, false);
    x = fmaxf(x, __int_as_float(r));
  }
  return __int_as_float(__builtin_amdgcn_readlane(__float_as_int(x), 63));
}
__device__ __forceinline__ float rfl(float x) {
  return __int_as_float(__builtin_amdgcn_readfirstlane(__float_as_int(x)));
}
__device__ __forceinline__ float clamp01(float x) {
  return __builtin_amdgcn_fmed3f(x, 0.f, 1.f);
}
__device__ __forceinline__ f16x2 pk2(float a, float b) {
  return __builtin_bit_cast(f16x2, __builtin_amdgcn_cvt_pkrtz(a, b));
}
__device__ __forceinline__ float dot2f(f16x2 a, f16x2 b, float c) {
  return __builtin_amdgcn_fdot2(a, b, c, false);   // v_dot2_f32_f16
}
// select 1-of-4 packed f16x2 by 2-bit index (3 cndmask)
__device__ __forceinline__ f16x2 selg2(f16x2 a0, f16x2 a1, f16x2 a2, f16x2 a3, int g) {
  const int i0 = __builtin_bit_cast(int, a0);
  const int i1 = __builtin_bit_cast(int, a1);
  const int i2 = __builtin_bit_cast(int, a2);
  const int i3 = __builtin_bit_cast(int, a3);
  const int ab = (g & 1) ? i1 : i0;
  const int cd = (g & 1) ? i3 : i2;
  return __builtin_bit_cast(f16x2, (g & 2) ? cd : ab);
}

__global__ __launch_bounds__(512, 4) void markowitz_kernel(
    const float* __restrict__ rets, const float* __restrict__ cov,
    const float* __restrict__ gam,  const float* __restrict__ alp,
    float* __restrict__ out)
{
  __shared__ char smem[LDS_BYTES] __attribute__((aligned(16)));
  float* STG  = (float*)smem;
  f16*   CH   = (f16*)(smem + OFF_CH);
  float* DTMP = (float*)(smem + OFF_YY0);   // 512 f32 overlay (YY0+YY1)

  const int t    = threadIdx.x;
  const int lane = t & 63;
  const int w8   = t >> 6;          // wave 0..7
  const int lm   = lane & 15;       // column-within-tile owner index
  const int hq   = lane >> 4;       // row-subgroup index

  const int b = blockIdx.x;
  const float g  = gam[b];
  const float aa = fabsf(alp[b]);
  const float* __restrict__ C = cov + (size_t)b * (NA * NA);

  const bool mk = ((lm >> 2) == hq);
  const int  cw = lm & 3;

  // ===== Phase 1: Q = (gC)^T(gC), f16-packed registers + exact f32 diag =====
  // ah[ii][j2][c] packs Q[16*(w8+8ii)+4hq+c][16*(2j2)+lm | 16*(2j2+1)+lm]
  f16x2 ah[2][8][4];
  float dacc = 0.f;

  #pragma unroll
  for (int pass = 0; pass < 2; ++pass) {
    f32x4 acc1[16];
    #pragma unroll
    for (int j = 0; j < 16; ++j) acc1[j] = f32x4{0.f, 0.f, 0.f, 0.f};

    #pragma unroll 1
    for (int kb = 0; kb < 16; ++kb) {
      { // stage 16x256 f32 (gamma-folded), coalesced
        const int kk = t >> 5;
        const int ib = (t & 31) << 3;
        const float* src = C + (size_t)(kb * 16 + kk) * NA + ib;
        float* dst = STG + kk * CSTR + ib;
        float4 c0 = *(const float4*)(src);
        float4 c1 = *(const float4*)(src + 4);
        *(float4*)(dst)     = make_float4(c0.x * g, c0.y * g, c0.z * g, c0.w * g);
        *(float4*)(dst + 4) = make_float4(c1.x * g, c1.y * g, c1.z * g, c1.w * g);
      }
      __syncthreads();
      { // transpose to f16 C^T tile; pass 0 also accumulates exact diag
        const int ti = t & 255;
        const int th = t >> 8;       // k-half 0/1
        f16x8 vh;
        #pragma unroll
        for (int s2 = 0; s2 < 8; ++s2) {
          const float x = STG[(8 * th + s2) * CSTR + ti];
          if (pass == 0) dacc += x * x;
          vh[s2] = (f16)x;
        }
        *(f16x8*)(CH + ti * TSTR + 8 * th) = vh;
      }
      __syncthreads();
      const int I = w8 + 8 * pass;
      const f16x4 aH = *(const f16x4*)(CH + (16 * I + lm) * TSTR + 4 * hq);
      #pragma unroll
      for (int J = 0; J < 16; ++J) {
        const f16x4 bH = *(const f16x4*)(CH + (16 * J + lm) * TSTR + 4 * hq);
        acc1[J] = __builtin_amdgcn_mfma_f32_16x16x16f16(aH, bH, acc1[J], 0, 0, 0);
      }
    }
    // pack to f16 pairs (canonical); zero diag slot (handled exactly via dgv)
    const int dj = w8 + 8 * pass;
    #pragma unroll
    for (int j2 = 0; j2 < 8; ++j2) {
      #pragma unroll
      for (int c = 0; c < 4; ++c) {
        float a0 = acc1[2 * j2][c];
        float a1 = acc1[2 * j2 + 1][c];
        if (2 * j2     == dj && lm == 4 * hq + c) a0 = 0.f;
        if (2 * j2 + 1 == dj && lm == 4 * hq + c) a1 = 0.f;
        ah[pass][j2][c] = pk2(a0, a1);
      }
    }
  }

  // exact diag sums -> LDS overlay
  {
    const int ti = t & 255;
    const int th = t >> 8;
    DTMP[th * 256 + ti] = dacc;
  }
  __syncthreads();
  float dg0 = 0.f, dg1 = 0.f;
  if (mk) {
    const int c0 = 16 * w8 + lm, c1 = 16 * (w8 + 8) + lm;
    dg0 = DTMP[c0] + DTMP[256 + c0] + aa;
    dg1 = DTMP[c1] + DTMP[256 + c1] + aa;
  }
  f32x4 dgv0, dgv1;
  #pragma unroll
  for (int p = 0; p < 4; ++p) {
    dgv0[p] = (lm == 4 * hq + p) ? dg0 : 0.f;
    dgv1[p] = (lm == 4 * hq + p) ? dg1 : 0.f;
  }
  __syncthreads();   // DTMP dead

  float* const YY0 = (float*)(smem + OFF_YY0);
  float* const YY1 = (float*)(smem + OFF_YY1);

  // Row-relative z storage: zr[g][c] = z[16*(4*(hq^g)+c) + lm]. All static.
  float zr[4][4];
  #pragma unroll
  for (int gg = 0; gg < 4; ++gg)
    #pragma unroll
    for (int c = 0; c < 4; ++c) zr[gg][c] = 1.f;   // power b0 = ones

  // matvec: canonical zpk assembled from zr via selg2 (g = q^hq).
  auto matvec = [&](f32x4& y0, f32x4& y1) {
    f16x2 zrpk[4][2];
    #pragma unroll
    for (int gg = 0; gg < 4; ++gg) {
      zrpk[gg][0] = pk2(zr[gg][0], zr[gg][1]);
      zrpk[gg][1] = pk2(zr[gg][2], zr[gg][3]);
    }
    f16x2 zpk[8];
    #pragma unroll
    for (int j2 = 0; j2 < 8; ++j2) {
      const int q = j2 >> 1, pb = j2 & 1;
      zpk[j2] = selg2(zrpk[0][pb], zrpk[1][pb], zrpk[2][pb], zrpk[3][pb], q ^ hq);
    }
    // exact f32 diag z: zd0 = z[16*w8+lm], zd1 = z[16*(w8+8)+lm]
    float zd0 = 0.f, zd1 = 0.f;
    {
      const int g0 = (w8 >> 2) ^ hq;      // zd1 uses g0^2
      const int cc0 = w8 & 3;             // wave-uniform
      #pragma unroll
      for (int cc = 0; cc < 4; ++cc)
        if (cc0 == cc) {
          const float ab = (g0 & 1) ? zr[1][cc] : zr[0][cc];
          const float cd = (g0 & 1) ? zr[3][cc] : zr[2][cc];
          zd0 = (g0 & 2) ? cd : ab;
          zd1 = (g0 & 2) ? ab : cd;
        }
    }
    y0 = dgv0 * zd0;
    y1 = dgv1 * zd1;
    #pragma unroll
    for (int j2 = 0; j2 < 8; ++j2) {
      #pragma unroll
      for (int c = 0; c < 4; ++c) {
        y0[c] = dot2f(ah[0][j2][c], zpk[j2], y0[c]);
        y1[c] = dot2f(ah[1][j2][c], zpk[j2], y1[c]);
      }
    }
    #pragma unroll
    for (int c = 0; c < 4; ++c) { y0[c] = red16(y0[c]); y1[c] = red16(y1[c]); }
  };
  auto publish = [&](float* YYp, const f32x4& y0, const f32x4& y1) {
    if (mk) {
      const float ya = (cw == 0) ? y0[0] : (cw == 1) ? y0[1] : (cw == 2) ? y0[2] : y0[3];
      const float yb = (cw == 0) ? y1[0] : (cw == 1) ? y1[1] : (cw == 2) ? y1[2] : y1[3];
      YYp[16 * w8 + lm]       = ya;
      YYp[16 * (w8 + 8) + lm] = yb;
    }
  };

  // ===== Phase 2: power iteration + Rayleigh step (1 barrier/iter) =====
  float step;
  {
    #pragma unroll 1
    for (int pi = 0; pi < POWER_ITERS; ++pi) {
      f32x4 y0, y1; matvec(y0, y1);
      float* YYp = (pi & 1) ? YY1 : YY0;
      publish(YYp, y0, y1);
      __syncthreads();
      float nrm = 0.f;
      #pragma unroll
      for (int gg = 0; gg < 4; ++gg)
        #pragma unroll
        for (int c = 0; c < 4; ++c) {
          const float tv = YYp[(((hq ^ gg) * 4 + c) << 4) + lm];
          nrm += tv * tv;
          zr[gg][c] = tv;
        }
      nrm = rfl(red16(nrm));
      const float rb = 1.f / (sqrtf(nrm) + 1e-12f);
      #pragma unroll
      for (int gg = 0; gg < 4; ++gg)
        #pragma unroll
        for (int c = 0; c < 4; ++c) zr[gg][c] *= rb;
    }
    f32x4 y0, y1; matvec(y0, y1);             // lambda = b^T Q b
    publish(YY0, y0, y1);
    __syncthreads();
    float lam = 0.f;
    #pragma unroll
    for (int gg = 0; gg < 4; ++gg)
      #pragma unroll
      for (int c = 0; c < 4; ++c)
        lam += zr[gg][c] * YY0[(((hq ^ gg) * 4 + c) << 4) + lm];
    lam = rfl(red16(lam));
    step = 1.f / (2.f * lam + 1e-6f);
  }

  // ===== Phase 3: FISTA — quarter-split state, 1 barrier/iter =====
  float wo4[4], rr4[4];
  #pragma unroll
  for (int c = 0; c < 4; ++c) {
    rr4[c] = rets[b * NA + ((4 * hq + c) << 4) + lm];
    wo4[c] = 1.f / 256.f;
  }
  #pragma unroll
  for (int gg = 0; gg < 4; ++gg)
    #pragma unroll
    for (int c = 0; c < 4; ++c) zr[gg][c] = 1.f / 256.f;
  float tt = 1.f;
  float tauw = 1e30f;
  float kest = 32.f;

  #pragma unroll 1
  for (int it = 0; it < PGD_ITERS; ++it) {
    f32x4 y0, y1; matvec(y0, y1);
    float* YYp = (it & 1) ? YY0 : YY1;
    publish(YYp, y0, y1);
    __syncthreads();

    // own columns only: v = z - step*(2y - r)
    float vq[4];
    #pragma unroll
    for (int c = 0; c < 4; ++c) {
      const float yv = YYp[((4 * hq + c) << 4) + lm];
      vq[c] = zr[0][c] - step * (2.f * yv - rr4[c]);
    }

    // Projection (verified R10/R12/R14/R16): uniform-scalar secant with
    // early exit; vq IS the lane's quarter (extraction eliminated).
    float lo = -1e30f, hi = 1e30f;
    float tau = tauw;
    float fprev = 0.f, tprev = 0.f;
    bool have = false;
    #pragma unroll 1
    for (int nit = 0; nit < 16; ++nit) {
      float sp = clamp01(vq[0] - tau) + clamp01(vq[1] - tau)
               + clamp01(vq[2] - tau) + clamp01(vq[3] - tau);
      const float s = redwave_add(sp);
      if (nit == 0) {
        const float pm = redwave_max(fmaxf(fmaxf(vq[0], vq[1]), fmaxf(vq[2], vq[3])));
        lo = pm - 1.0f; hi = pm;              // root always in [max-1, max]
        if (!(tau > lo && tau < hi)) { tau = 0.5f * (lo + hi); continue; }
      }
      const float f = s - 1.f;
      if (fabsf(f) <= 1e-5f) break;
      if (f > 0.f) lo = tau; else hi = tau;
      if (hi - lo < 1e-7f) break;
      float kc = have ? ((f - fprev) / (tprev - tau)) : kest;
      if (!(kc > 0.5f)) kc = kest;
      const float tn = tau + f / kc;
      fprev = f; tprev = tau; have = true;
      kest = fmaxf(kc, 1.f);
      const float tc = (tn > lo && tn < hi) ? tn : 0.5f * (lo + hi);
      if (tc == tau) break;
      tau = tc;
    }
    tauw = tau;

    const float tnew = 0.5f * (1.f + sqrtf(1.f + 4.f * tt * tt));
    const float coef = (tt - 1.f) / tnew;
    const bool last = (it == PGD_ITERS - 1);
    float zn[4];
    #pragma unroll
    for (int c = 0; c < 4; ++c) {
      const float wn = clamp01(vq[c] - tau);
      zn[c] = wn + coef * (wn - wo4[c]);
      wo4[c] = wn;
      if (last && w8 == 0) out[(size_t)b * NA + ((4 * hq + c) << 4) + lm] = wn;
    }
    tt = tnew;

    // f32-exact 3-way exchange refills the row-relative replicas
    #pragma unroll
    for (int c = 0; c < 4; ++c) {
      zr[0][c] = zn[c];
      zr[1][c] = __shfl_xor(zn[c], 16);
      zr[2][c] = __shfl_xor(zn[c], 32);
      zr[3][c] = __shfl_xor(zn[c], 48);
    }
  }
}

extern "C" void kernel_launch(void* const* d_in, const int* in_sizes, int n_in,
                              void* d_out, int out_size, void* d_ws, size_t ws_size,
                              hipStream_t stream) {
  (void)in_sizes; (void)n_in; (void)out_size; (void)d_ws; (void)ws_size;
  const float* rets = (const float*)d_in[0];
  const float* cov  = (const float*)d_in[1];
  const float* gam  = (const float*)d_in[2];
  const float* alp  = (const float*)d_in[3];
  float* out = (float*)d_out;
  hipLaunchKernelGGL(markowitz_kernel, dim3(NS), dim3(512), 0, stream,
                     rets, cov, gam, alp, out);
}